// Round 1
// baseline (173.961 us; speedup 1.0000x reference)
//
#include <hip/hip_runtime.h>
#include <stdint.h>
#include <math.h>

typedef float  f32x4 __attribute__((ext_vector_type(4)));
typedef float  f32x2 __attribute__((ext_vector_type(2)));
typedef short  s16x8 __attribute__((ext_vector_type(8)));
typedef short  s16x4 __attribute__((ext_vector_type(4)));

#define KC   1024      // codebook size
#define DD   256       // vector dim
#define NR   32768     // rows (32*32*32)

// workspace layout (bytes)
#define WS_HIST   0         // 1024 x u32
#define WS_ACC    4096      // 2 x f32  (sum_x2, sum_minscore)
#define WS_E2     8192      // 1024 x f32
#define WS_IDX    12288     // 32768 x i32
#define WS_PANEL  143360    // 1024*256 bf16 (row-major, 512 B/row)

__device__ __forceinline__ short f2bf(float f) {
    uint32_t u = __builtin_bit_cast(uint32_t, f);
    uint32_t r = (u + 0x7FFFu + ((u >> 16) & 1u)) >> 16;   // RNE
    return (short)r;
}

// ---- kernel 0: bf16 codebook panel + e2[k] + zero hist/accums -------------
__global__ void k_prep(const float* __restrict__ emb, char* __restrict__ ws) {
    int tid = threadIdx.x;
    if (blockIdx.x == 0) {
        uint32_t* hist = (uint32_t*)(ws + WS_HIST);
        #pragma unroll
        for (int j = 0; j < 4; j++) hist[tid * 4 + j] = 0u;
        if (tid < 2) ((float*)(ws + WS_ACC))[tid] = 0.f;
    }
    int wid = tid >> 6, lane = tid & 63;
    int code = blockIdx.x * 4 + wid;                 // 256 blocks x 4 waves
    const float* row = emb + (size_t)code * DD;
    f32x4 v = *(const f32x4*)(row + lane * 4);
    s16x4 b;
    b[0] = f2bf(v.x); b[1] = f2bf(v.y); b[2] = f2bf(v.z); b[3] = f2bf(v.w);
    *(s16x4*)((short*)(ws + WS_PANEL) + (size_t)code * DD + lane * 4) = b;
    float ss = v.x * v.x + v.y * v.y + v.z * v.z + v.w * v.w;
    #pragma unroll
    for (int off = 1; off < 64; off <<= 1) ss += __shfl_xor(ss, off);
    if (lane == 0) ((float*)(ws + WS_E2))[code] = ss;
}

// ---- kernel 1: bf16 MFMA distance GEMM + per-row argmin -------------------
// 1 wave per block (64 thr), 32 rows per wave, grid = 1024 blocks.
__global__ __launch_bounds__(64) void k_argmin(const float* __restrict__ latents,
                                               char* __restrict__ ws) {
    const short* panel = (const short*)(ws + WS_PANEL);
    const float* e2    = (const float*)(ws + WS_E2);
    uint32_t*    hist  = (uint32_t*)(ws + WS_HIST);
    float*       acc   = (float*)(ws + WS_ACC);
    int*         idxo  = (int*)(ws + WS_IDX);

    int lane = threadIdx.x & 63;
    int g = lane >> 4, r16 = lane & 15;
    int wavebase = blockIdx.x * 32;

    // A fragments: 2 row-tiles x 8 k-steps, per-lane 8 bf16 each.
    s16x8 af[2][8];
    float x2part = 0.f;
    #pragma unroll
    for (int rt = 0; rt < 2; rt++) {
        int n = wavebase + rt * 16 + r16;
        int b = n >> 10, hw = n & 1023;
        const float* src = latents + (size_t)b * 262144 + hw;
        #pragma unroll
        for (int kt = 0; kt < 8; kt++) {
            s16x8 a;
            #pragma unroll
            for (int j = 0; j < 8; j++) {
                int d = kt * 32 + g * 8 + j;
                float x = src[(size_t)d * 1024];
                x2part += x * x;
                a[j] = f2bf(x);
            }
            af[rt][kt] = a;
        }
    }

    float vmin[2][4];
    int   vidx[2][4];
    #pragma unroll
    for (int rt = 0; rt < 2; rt++)
        #pragma unroll
        for (int j = 0; j < 4; j++) { vmin[rt][j] = 3.4e38f; vidx[rt][j] = 0; }

    for (int c = 0; c < 64; c++) {                    // 64 chunks of 16 codes
        int cbase = c * 16;
        const short* prow = panel + (size_t)(cbase + r16) * DD + g * 8;
        s16x8 bf[8];
        #pragma unroll
        for (int kt = 0; kt < 8; kt++) bf[kt] = *(const s16x8*)(prow + kt * 32);
        float e2c = e2[cbase + r16];
        #pragma unroll
        for (int rt = 0; rt < 2; rt++) {
            f32x4 a4 = {0.f, 0.f, 0.f, 0.f};
            #pragma unroll
            for (int kt = 0; kt < 8; kt++)
                a4 = __builtin_amdgcn_mfma_f32_16x16x32_bf16(af[rt][kt], bf[kt], a4, 0, 0, 0);
            #pragma unroll
            for (int j = 0; j < 4; j++) {
                float s = e2c - 2.f * a4[j];          // score for row 4g+j, col cbase+r16
                bool better = s < vmin[rt][j];
                vmin[rt][j] = better ? s : vmin[rt][j];
                vidx[rt][j] = better ? (cbase + r16) : vidx[rt][j];
            }
        }
    }

    float minsum = 0.f;
    #pragma unroll
    for (int rt = 0; rt < 2; rt++) {
        #pragma unroll
        for (int j = 0; j < 4; j++) {
            float s = vmin[rt][j]; int ii = vidx[rt][j];
            #pragma unroll
            for (int off = 1; off < 16; off <<= 1) {   // reduce over 16 cols
                float os = __shfl_xor(s, off);
                int   oi = __shfl_xor(ii, off);
                if (os < s || (os == s && oi < ii)) { s = os; ii = oi; }
            }
            minsum += s;
            if (r16 == 0) {
                int n = wavebase + rt * 16 + g * 4 + j;
                idxo[n] = ii;
                atomicAdd(hist + ii, 1u);
            }
        }
    }
    // groups hold disjoint rows; within-group lanes identical -> add across groups
    minsum += __shfl_xor(minsum, 16);
    minsum += __shfl_xor(minsum, 32);
    #pragma unroll
    for (int off = 1; off < 64; off <<= 1) x2part += __shfl_xor(x2part, off);
    if (lane == 0) { atomicAdd(acc + 0, x2part); atomicAdd(acc + 1, minsum); }
}

// ---- kernel 2: quantized output (gather + transpose to [B,D,H,W]) ---------
__global__ void k_quant(const float* __restrict__ emb, const char* __restrict__ ws,
                        float* __restrict__ out) {
    const int* idx = (const int*)(ws + WS_IDX);
    int tid = threadIdx.x;
    int dg  = blockIdx.x & 63;
    int hwt = (blockIdx.x >> 6) & 3;
    int b   = blockIdx.x >> 8;
    int hw  = hwt * 256 + tid;
    int n   = b * 1024 + hw;
    int code = idx[n];
    f32x4 v = *(const f32x4*)(emb + (size_t)code * 256 + dg * 4);
    float* dst = out + 1 + (size_t)b * 262144 + (size_t)dg * 4096 + hw;
    dst[0] = v.x; dst[1024] = v.y; dst[2048] = v.z; dst[3072] = v.w;
}

// ---- kernel 3: one-hot encodings (134 MB streaming write) -----------------
__global__ void k_onehot(const char* __restrict__ ws, float* __restrict__ out) {
    const int* idx = (const int*)(ws + WS_IDX);
    __shared__ int lidx[8];
    int tid = threadIdx.x;
    int rbase = blockIdx.x * 8;
    if (tid < 8) lidx[tid] = idx[rbase + tid];
    __syncthreads();
    f32x2* enc = (f32x2*)(out + 8388610);             // 8B-aligned region
    #pragma unroll
    for (int j = 0; j < 16; j++) {
        int linear = j * 256 + tid;                   // 0..4095 float2 in block
        int rl = linear >> 9, c2 = linear & 511;
        int id = lidx[rl];
        f32x2 v;
        v.x = (2 * c2     == id) ? 1.f : 0.f;
        v.y = (2 * c2 + 1 == id) ? 1.f : 0.f;
        enc[(size_t)(rbase + rl) * 512 + c2] = v;
    }
}

// ---- kernel 4: loss + perplexity ------------------------------------------
__global__ void k_final(const char* __restrict__ ws, float* __restrict__ out) {
    __shared__ float red[256];
    const uint32_t* hist = (const uint32_t*)(ws + WS_HIST);
    const float*    acc  = (const float*)(ws + WS_ACC);
    int tid = threadIdx.x;
    float part = 0.f;
    #pragma unroll
    for (int j = 0; j < 4; j++) {
        float p = (float)hist[tid * 4 + j] * (1.f / 32768.f);
        part += p * logf(p + 1e-10f);
    }
    red[tid] = part;
    __syncthreads();
    for (int s = 128; s > 0; s >>= 1) {
        if (tid < s) red[tid] += red[tid + s];
        __syncthreads();
    }
    if (tid == 0) {
        out[8388609] = expf(-red[0]);                              // perplexity
        out[0] = 1.25f * (acc[0] + acc[1]) * (1.f / 8388608.f);    // loss
    }
}

extern "C" void kernel_launch(void* const* d_in, const int* in_sizes, int n_in,
                              void* d_out, int out_size, void* d_ws, size_t ws_size,
                              hipStream_t stream) {
    const float* latents = (const float*)d_in[0];
    const float* emb     = (const float*)d_in[1];
    float* out = (float*)d_out;
    char*  ws  = (char*)d_ws;

    hipLaunchKernelGGL(k_prep,   dim3(256),  dim3(256), 0, stream, emb, ws);
    hipLaunchKernelGGL(k_argmin, dim3(1024), dim3(64),  0, stream, latents, ws);
    hipLaunchKernelGGL(k_quant,  dim3(8192), dim3(256), 0, stream, emb, ws, out);
    hipLaunchKernelGGL(k_onehot, dim3(4096), dim3(256), 0, stream, ws, out);
    hipLaunchKernelGGL(k_final,  dim3(1),    dim3(256), 0, stream, ws, out);
}

// Round 2
// 160.228 us; speedup vs baseline: 1.0857x; 1.0857x over previous
//
#include <hip/hip_runtime.h>
#include <stdint.h>
#include <math.h>

typedef float  f32x4 __attribute__((ext_vector_type(4)));
typedef float  f32x2 __attribute__((ext_vector_type(2)));
typedef short  s16x8 __attribute__((ext_vector_type(8)));
typedef short  s16x4 __attribute__((ext_vector_type(4)));

#define KC   1024      // codebook size
#define DD   256       // vector dim
#define NR   32768     // rows (32*32*32)

// workspace layout (bytes)
#define WS_HIST   0         // 1024 x u32
#define WS_ACC    4096      // 2 x f32  (sum_x2, sum_minscore)
#define WS_E2     8192      // 1024 x f32
#define WS_IDX    12288     // 32768 x i32
#define WS_PANEL  143360    // 1024*256 bf16 (row-major, 512 B/row)

__device__ __forceinline__ short f2bf(float f) {
    uint32_t u = __builtin_bit_cast(uint32_t, f);
    uint32_t r = (u + 0x7FFFu + ((u >> 16) & 1u)) >> 16;   // RNE
    return (short)r;
}

// ---- kernel 0: bf16 codebook panel + e2[k] + zero hist/accums -------------
__global__ void k_prep(const float* __restrict__ emb, char* __restrict__ ws) {
    int tid = threadIdx.x;
    if (blockIdx.x == 0) {
        uint32_t* hist = (uint32_t*)(ws + WS_HIST);
        #pragma unroll
        for (int j = 0; j < 4; j++) hist[tid * 4 + j] = 0u;
        if (tid < 2) ((float*)(ws + WS_ACC))[tid] = 0.f;
    }
    int wid = tid >> 6, lane = tid & 63;
    int code = blockIdx.x * 4 + wid;                 // 256 blocks x 4 waves
    const float* row = emb + (size_t)code * DD;
    f32x4 v = *(const f32x4*)(row + lane * 4);
    s16x4 b;
    b[0] = f2bf(v.x); b[1] = f2bf(v.y); b[2] = f2bf(v.z); b[3] = f2bf(v.w);
    *(s16x4*)((short*)(ws + WS_PANEL) + (size_t)code * DD + lane * 4) = b;
    float ss = v.x * v.x + v.y * v.y + v.z * v.z + v.w * v.w;
    #pragma unroll
    for (int off = 1; off < 64; off <<= 1) ss += __shfl_xor(ss, off);
    if (lane == 0) ((float*)(ws + WS_E2))[code] = ss;
}

// ---- kernel 1: bf16 MFMA distance GEMM + per-row argmin -------------------
// 1024 blocks x 256 thr (4 waves). Block owns 32 rows; each wave scores
// those rows against its own 256-code slice; cross-wave combine in LDS.
__global__ __launch_bounds__(256, 4) void k_argmin(const float* __restrict__ latents,
                                                   char* __restrict__ ws) {
    const short* panel = (const short*)(ws + WS_PANEL);
    const float* e2    = (const float*)(ws + WS_E2);
    uint32_t*    hist  = (uint32_t*)(ws + WS_HIST);
    float*       acc   = (float*)(ws + WS_ACC);
    int*         idxo  = (int*)(ws + WS_IDX);

    __shared__ __align__(16) char smem[16384];   // 32 rows x 512 B (swizzled bf16)

    int t = threadIdx.x;
    int nbase = blockIdx.x * 32;
    int b = nbase >> 10, hwbase = nbase & 1023;

    // ---- stage A tile (coalesced float4) + x2 partial -----------------
    {
        int hw4 = (t & 7) * 4;                   // row group of 4
        int d0  = t >> 3;                        // 0..31
        const float* base = latents + (size_t)b * 262144 + hwbase + hw4;
        float xs = 0.f;
        #pragma unroll
        for (int i = 0; i < 8; i++) {
            int d = d0 + i * 32;
            f32x4 v = *(const f32x4*)(base + (size_t)d * 1024);
            #pragma unroll
            for (int q = 0; q < 4; q++) {
                float x = v[q];
                xs += x * x;
                int r = hw4 + q;
                int blk = (d >> 3) ^ (r & 7);
                *(short*)(smem + r * 512 + blk * 16 + (d & 7) * 2) = f2bf(x);
            }
        }
        #pragma unroll
        for (int off = 1; off < 64; off <<= 1) xs += __shfl_xor(xs, off);
        if ((t & 63) == 0) atomicAdd(acc + 0, xs);
    }
    __syncthreads();

    int lane = t & 63;
    int wid  = t >> 6;
    int g = lane >> 4, r16 = lane & 15;

    // ---- A fragments from LDS: 2 row-tiles x 8 k-steps ---------------
    s16x8 af[2][8];
    #pragma unroll
    for (int rt = 0; rt < 2; rt++) {
        int r = rt * 16 + r16;
        #pragma unroll
        for (int kt = 0; kt < 8; kt++) {
            int blk = (kt * 4 + g) ^ (r & 7);
            af[rt][kt] = *(const s16x8*)(smem + r * 512 + blk * 16);
        }
    }
    __syncthreads();   // LDS will be reused for the cross-wave combine

    float vmin[2][4];
    int   vidx[2][4];
    #pragma unroll
    for (int rt = 0; rt < 2; rt++)
        #pragma unroll
        for (int j = 0; j < 4; j++) { vmin[rt][j] = 3.4e38f; vidx[rt][j] = 0; }

    int codebase = wid * 256;
    for (int c = 0; c < 16; c++) {                // 16 chunks of 16 codes
        int cbase = codebase + c * 16;
        const short* prow = panel + (size_t)(cbase + r16) * DD + g * 8;
        s16x8 bf[8];
        #pragma unroll
        for (int kt = 0; kt < 8; kt++) bf[kt] = *(const s16x8*)(prow + kt * 32);
        float e2c = e2[cbase + r16];
        #pragma unroll
        for (int rt = 0; rt < 2; rt++) {
            f32x4 a4 = {0.f, 0.f, 0.f, 0.f};
            #pragma unroll
            for (int kt = 0; kt < 8; kt++)
                a4 = __builtin_amdgcn_mfma_f32_16x16x32_bf16(af[rt][kt], bf[kt], a4, 0, 0, 0);
            #pragma unroll
            for (int j = 0; j < 4; j++) {
                float s = e2c - 2.f * a4[j];      // row 4g+j, col cbase+r16
                bool better = s < vmin[rt][j];
                vmin[rt][j] = better ? s : vmin[rt][j];
                vidx[rt][j] = better ? (cbase + r16) : vidx[rt][j];
            }
        }
    }

    // ---- per-wave 16-lane reduce, stash to LDS ------------------------
    float* Lf = (float*)smem;          // [4][32] mins
    int*   Li = (int*)smem + 128;      // [4][32] idx
    #pragma unroll
    for (int rt = 0; rt < 2; rt++) {
        #pragma unroll
        for (int j = 0; j < 4; j++) {
            float s = vmin[rt][j]; int ii = vidx[rt][j];
            #pragma unroll
            for (int off = 1; off < 16; off <<= 1) {
                float os = __shfl_xor(s, off);
                int   oi = __shfl_xor(ii, off);
                if (os < s || (os == s && oi < ii)) { s = os; ii = oi; }
            }
            if (r16 == 0) {
                int row = rt * 16 + g * 4 + j;
                Lf[wid * 32 + row] = s;
                Li[wid * 32 + row] = ii;
            }
        }
    }
    __syncthreads();

    // ---- cross-wave combine (threads 0..31) ---------------------------
    if (t < 32) {
        int row = t;
        float s = Lf[row]; int ii = Li[row];
        #pragma unroll
        for (int w = 1; w < 4; w++) {
            float os = Lf[w * 32 + row];
            int   oi = Li[w * 32 + row];
            if (os < s || (os == s && oi < ii)) { s = os; ii = oi; }
        }
        idxo[nbase + row] = ii;
        atomicAdd(hist + ii, 1u);
        #pragma unroll
        for (int off = 1; off < 32; off <<= 1) s += __shfl_xor(s, off);
        if (t == 0) atomicAdd(acc + 1, s);
    }
}

// ---- kernel 2: quantized output (gather + transpose to [B,D,H,W]) ---------
__global__ void k_quant(const float* __restrict__ emb, const char* __restrict__ ws,
                        float* __restrict__ out) {
    const int* idx = (const int*)(ws + WS_IDX);
    int tid = threadIdx.x;
    int dg  = blockIdx.x & 63;
    int hwt = (blockIdx.x >> 6) & 3;
    int b   = blockIdx.x >> 8;
    int hw  = hwt * 256 + tid;
    int n   = b * 1024 + hw;
    int code = idx[n];
    f32x4 v = *(const f32x4*)(emb + (size_t)code * 256 + dg * 4);
    float* dst = out + 1 + (size_t)b * 262144 + (size_t)dg * 4096 + hw;
    dst[0] = v.x; dst[1024] = v.y; dst[2048] = v.z; dst[3072] = v.w;
}

// ---- kernel 3: one-hot encodings (134 MB streaming write) -----------------
__global__ void k_onehot(const char* __restrict__ ws, float* __restrict__ out) {
    const int* idx = (const int*)(ws + WS_IDX);
    __shared__ int lidx[8];
    int tid = threadIdx.x;
    int rbase = blockIdx.x * 8;
    if (tid < 8) lidx[tid] = idx[rbase + tid];
    __syncthreads();
    f32x2* enc = (f32x2*)(out + 8388610);             // 8B-aligned region
    #pragma unroll
    for (int j = 0; j < 16; j++) {
        int linear = j * 256 + tid;                   // 0..4095 float2 in block
        int rl = linear >> 9, c2 = linear & 511;
        int id = lidx[rl];
        f32x2 v;
        v.x = (2 * c2     == id) ? 1.f : 0.f;
        v.y = (2 * c2 + 1 == id) ? 1.f : 0.f;
        enc[(size_t)(rbase + rl) * 512 + c2] = v;
    }
}

// ---- kernel 4: loss + perplexity ------------------------------------------
__global__ void k_final(const char* __restrict__ ws, float* __restrict__ out) {
    __shared__ float red[256];
    const uint32_t* hist = (const uint32_t*)(ws + WS_HIST);
    const float*    acc  = (const float*)(ws + WS_ACC);
    int tid = threadIdx.x;
    float part = 0.f;
    #pragma unroll
    for (int j = 0; j < 4; j++) {
        float p = (float)hist[tid * 4 + j] * (1.f / 32768.f);
        part += p * logf(p + 1e-10f);
    }
    red[tid] = part;
    __syncthreads();
    for (int s = 128; s > 0; s >>= 1) {
        if (tid < s) red[tid] += red[tid + s];
        __syncthreads();
    }
    if (tid == 0) {
        out[8388609] = expf(-red[0]);                              // perplexity
        out[0] = 1.25f * (acc[0] + acc[1]) * (1.f / 8388608.f);    // loss
    }
}

extern "C" void kernel_launch(void* const* d_in, const int* in_sizes, int n_in,
                              void* d_out, int out_size, void* d_ws, size_t ws_size,
                              hipStream_t stream) {
    const float* latents = (const float*)d_in[0];
    const float* emb     = (const float*)d_in[1];
    float* out = (float*)d_out;
    char*  ws  = (char*)d_ws;

    hipLaunchKernelGGL(k_prep,   dim3(256),  dim3(256), 0, stream, emb, ws);
    hipLaunchKernelGGL(k_argmin, dim3(1024), dim3(256), 0, stream, latents, ws);
    hipLaunchKernelGGL(k_quant,  dim3(8192), dim3(256), 0, stream, emb, ws, out);
    hipLaunchKernelGGL(k_onehot, dim3(4096), dim3(256), 0, stream, ws, out);
    hipLaunchKernelGGL(k_final,  dim3(1),    dim3(256), 0, stream, ws, out);
}